// Round 8
// baseline (278.700 us; speedup 1.0000x reference)
//
#include <hip/hip_runtime.h>
#include <stdint.h>

typedef __attribute__((ext_vector_type(8))) unsigned short ushort8;
typedef __attribute__((ext_vector_type(8))) __bf16 bf16x8;
typedef __attribute__((ext_vector_type(4))) float f32x4;
typedef __attribute__((ext_vector_type(4))) uint32_t u32x4;

__device__ __forceinline__ unsigned short f2bf(float f) {
  union { float f; uint32_t u; } x; x.f = f;
  uint32_t u = x.u;
  uint32_t r = (u + 0x7fffu + ((u >> 16) & 1u)) >> 16;
  return (unsigned short)r;
}

// round-half-up bf16 pair pack: 2 adds + 1 v_perm (≡ RNE for positive non-ties)
__device__ __forceinline__ uint32_t rhu2(float lo, float hi) {
  union { float f; uint32_t u; } a, b; a.f = lo; b.f = hi;
  return __builtin_amdgcn_perm(b.u + 0x8000u, a.u + 0x8000u, 0x07060302u);
}

__device__ __forceinline__ void store_c(unsigned short* p, float v) { *p = f2bf(v); }
__device__ __forceinline__ void store_c(float* p, float v) { *p = v; }

__device__ __forceinline__ void gll16(const unsigned short* g, unsigned short* l) {
  __builtin_amdgcn_global_load_lds((const __attribute__((address_space(1))) void*)g,
                                   (__attribute__((address_space(3))) void*)l,
                                   16, 0, 0);
}

// ---------------------------------------------------------------------------
// Weight transpose + convert: WT[n][k] = bf16(W[k][n]), 1024x1024 fp32 in.
// Batched x3 (wq/wk/wv) via blockIdx.z; single version kept for wo.
// ---------------------------------------------------------------------------
__device__ __forceinline__ void transpose_body(const float* W, unsigned short* WT) {
  __shared__ unsigned short tile[32][33];
  int c0 = blockIdx.x * 32, r0 = blockIdx.y * 32;
  int x = threadIdx.x, y = threadIdx.y;
#pragma unroll
  for (int i = 0; i < 32; i += 8)
    tile[y + i][x] = f2bf(W[(size_t)(r0 + y + i) * 1024 + c0 + x]);
  __syncthreads();
#pragma unroll
  for (int i = 0; i < 32; i += 8)
    WT[(size_t)(c0 + y + i) * 1024 + r0 + x] = tile[x][y + i];
}

__global__ void transpose_w(const float* __restrict__ W,
                            unsigned short* __restrict__ WT) {
  transpose_body(W, WT);
}

__global__ void transpose_w3(const float* W0, const float* W1, const float* W2,
                             unsigned short* T0, unsigned short* T1,
                             unsigned short* T2) {
  const float* W = (blockIdx.z == 0) ? W0 : (blockIdx.z == 1) ? W1 : W2;
  unsigned short* WT = (blockIdx.z == 0) ? T0 : (blockIdx.z == 1) ? T1 : T2;
  transpose_body(W, WT);
}

// ---------------------------------------------------------------------------
// GEMM (gemm3, R13-verified structure): C[M,N] = A[M,K]*B[K,N] given BT[N,K].
// 128x128 tile, BK=64, 256 thr (4 waves as 2m x 2n, each 64x64 out).
// Double-buffered LDS = 64 KB -> 2 blocks/CU (TLP beats pipeline depth here:
// R12/R15 1-block/CU configs both regressed). ONE barrier per K-step;
// STAGE(t+1) issued after the barrier so it is never drained by it.
// Both-sides XOR swizzle (verified R11-R13): LDS chunk j of row r holds
// global chunk j^(r&7); reads XOR by fr&7.
// NEW (R17): AF32 path fuses the fp32->bf16 convert of A into staging:
//   after barrier: issue 2xfloat4 loads/line (A, t+1) + gll16 B (t+1)
//   kh0 MFMA; cvt+ds_write_b128 A(t+1) into buf^1 (swizzle on write addr);
//   kh1 MFMA.  Same race structure: buf^1's last reads completed before
//   this barrier; ds_writes drain at the next barrier's lgkmcnt(0).
// sc0: epilogue scale when blockIdx.z == 0 (folds attn head_scale*log2e
// into the q projection; 1.0f elsewhere).
// ---------------------------------------------------------------------------
template <typename OutT, bool AF32>
__global__ __launch_bounds__(256, 2) void gemm3(
    const unsigned short* A16, const float* A32,
    const unsigned short* BT0, const unsigned short* BT1, const unsigned short* BT2,
    OutT* C0, OutT* C1, OutT* C2,
    int M, int N, int K, float sc0) {
  const unsigned short* BT = (blockIdx.z == 0) ? BT0 : (blockIdx.z == 1) ? BT1 : BT2;
  OutT* C = (blockIdx.z == 0) ? C0 : (blockIdx.z == 1) ? C1 : C2;
  const float sc = (blockIdx.z == 0) ? sc0 : 1.0f;

  __shared__ __attribute__((aligned(16))) unsigned short As[2][128 * 64];
  __shared__ __attribute__((aligned(16))) unsigned short Bs[2][128 * 64];

  const int tid = threadIdx.x;
  const int wave = tid >> 6, lane = tid & 63;
  const int fr = lane & 15, fq = lane >> 4;
  const int wm = wave >> 1, wn = wave & 1;
  const int bm = blockIdx.x * 128, bn = blockIdx.y * 128;

  const int r8 = tid >> 3, c8 = tid & 7;
  const int s8 = c8 ^ (r8 & 7);
  const unsigned short* Ag = nullptr;
  const float* Ag32 = nullptr;
  if constexpr (AF32) Ag32 = A32 + (size_t)(bm + r8) * K + c8 * 8;
  else                Ag   = A16 + (size_t)(bm + r8) * K + s8 * 8;
  const unsigned short* Bg = BT + (size_t)(bn + r8) * K + s8 * 8;

  f32x4 acc[4][4] = {};
  const int rx = fr & 7;  // read-side swizzle (16B-chunk units)

  const int NT = K >> 6;

  auto cvt8 = [](float4 a0, float4 a1) {
    bf16x8 w;
    w[0] = (__bf16)a0.x; w[1] = (__bf16)a0.y; w[2] = (__bf16)a0.z; w[3] = (__bf16)a0.w;
    w[4] = (__bf16)a1.x; w[5] = (__bf16)a1.y; w[6] = (__bf16)a1.z; w[7] = (__bf16)a1.w;
    return w;
  };

  // prologue: tile 0 -> buffer 0
  if constexpr (AF32) {
#pragma unroll
    for (int i = 0; i < 4; i++) {
      float4 a0 = *(const float4*)(Ag32 + (size_t)(i * 32) * K);
      float4 a1 = *(const float4*)(Ag32 + (size_t)(i * 32) * K + 4);
      *(bf16x8*)&As[0][(i * 32 + r8) * 64 + s8 * 8] = cvt8(a0, a1);
    }
  } else {
#pragma unroll
    for (int i = 0; i < 4; i++)
      gll16(Ag + (size_t)(i * 32) * K, &As[0][(i * 32 + wave * 8) * 64]);
  }
#pragma unroll
  for (int i = 0; i < 4; i++)
    gll16(Bg + (size_t)(i * 32) * K, &Bs[0][(i * 32 + wave * 8) * 64]);

  int cur = 0;
  for (int t = 0; t < NT; ++t) {
    __syncthreads();  // drains STAGE(t); lgkmcnt(0) covers prior ds_writes

    const int b = cur ^ 1;
    float4 fa0[4], fa1[4];
    if (t + 1 < NT) {
      const size_t k0 = (size_t)(t + 1) * 64;
      if constexpr (AF32) {
#pragma unroll
        for (int i = 0; i < 4; i++) {
          fa0[i] = *(const float4*)(Ag32 + k0 + (size_t)(i * 32) * K);
          fa1[i] = *(const float4*)(Ag32 + k0 + (size_t)(i * 32) * K + 4);
        }
      } else {
#pragma unroll
        for (int i = 0; i < 4; i++)
          gll16(Ag + k0 + (size_t)(i * 32) * K, &As[b][(i * 32 + wave * 8) * 64]);
      }
#pragma unroll
      for (int i = 0; i < 4; i++)
        gll16(Bg + k0 + (size_t)(i * 32) * K, &Bs[b][(i * 32 + wave * 8) * 64]);
    }

    auto compute = [&](int kh) {
      bf16x8 af[4], bfr[4];
#pragma unroll
      for (int mt = 0; mt < 4; mt++)
        af[mt] = *(const bf16x8*)&As[cur][(wm * 64 + mt * 16 + fr) * 64 +
                                          (((kh * 4 + fq) ^ rx) * 8)];
#pragma unroll
      for (int nt = 0; nt < 4; nt++)
        bfr[nt] = *(const bf16x8*)&Bs[cur][(wn * 64 + nt * 16 + fr) * 64 +
                                           (((kh * 4 + fq) ^ rx) * 8)];
#pragma unroll
      for (int mt = 0; mt < 4; mt++)
#pragma unroll
        for (int nt = 0; nt < 4; nt++)
          acc[mt][nt] = __builtin_amdgcn_mfma_f32_16x16x32_bf16(af[mt], bfr[nt], acc[mt][nt], 0, 0, 0);
    };

    compute(0);
    if (AF32 && t + 1 < NT) {
#pragma unroll
      for (int i = 0; i < 4; i++)
        *(bf16x8*)&As[b][(i * 32 + r8) * 64 + s8 * 8] = cvt8(fa0[i], fa1[i]);
    }
    compute(1);

    cur ^= 1;
  }

#pragma unroll
  for (int mt = 0; mt < 4; mt++)
#pragma unroll
    for (int nt = 0; nt < 4; nt++)
#pragma unroll
      for (int r = 0; r < 4; r++) {
        int row = bm + wm * 64 + mt * 16 + fq * 4 + r;
        int col = bn + wn * 64 + nt * 16 + fr;
        store_c(&C[(size_t)row * N + col], acc[mt][nt][r] * sc);
      }
}

// ---------------------------------------------------------------------------
// Flash attention R17: R16 structure (T14 async V, free-drain barriers) +
// softmax output built via scalar float->bf16 casts (compiler emits
// v_cvt_pk_bf16_f32 per m240) instead of rhu2 bit-packing: ~32 fewer VALU
// instrs/iter in the issue-saturated phase. Same math (RNE vs RHU differs
// only on ties).
// ---------------------------------------------------------------------------
__global__ __launch_bounds__(256, 4) void attn_kernel(
    const unsigned short* q, const unsigned short* k,
    const unsigned short* v, unsigned short* o) {
  const int S = 2048, E = 1024;
  __shared__ __attribute__((aligned(16))) unsigned short Ksb[2 * 64 * 64];
  __shared__ __attribute__((aligned(16))) unsigned short Vtb[64 * 64];

  const int tid = threadIdx.x;
  const int wave = tid >> 6, lane = tid & 63;
  const int fr = lane & 15, fq = lane >> 4;
  const int q0 = blockIdx.x * 128;
  const int bh = blockIdx.y;
  const int b = bh >> 4, h = bh & 15;
  const size_t base = ((size_t)b * S) * E + (size_t)h * 64;

  bf16x8 aq[2][2];
#pragma unroll
  for (int qg = 0; qg < 2; qg++)
#pragma unroll
    for (int ks = 0; ks < 2; ks++)
      aq[qg][ks] = *(const bf16x8*)&q[base +
          (size_t)(q0 + qg * 64 + wave * 16 + fr) * E + ks * 32 + fq * 8];

  ushort8 ones_u;
#pragma unroll
  for (int j = 0; j < 8; j++) ones_u[j] = 0x3F80;  // bf16 1.0
  bf16x8 onesf = *(bf16x8*)&ones_u;

  f32x4 ot[2][4] = {};
  f32x4 osum[2] = {};

  const int srow = lane >> 3;
  const int scol = (((lane & 7) ^ srow) << 3);
  const unsigned short* Kg = k + base + (size_t)(wave * 16 + srow) * E + scol;

  const int rp = (tid & 31) * 2;
  const int dcv = (tid >> 5) * 8;
  const int u_ = rp & 31;
  const int slot = 32 * (rp >> 5) + 8 * ((u_ & 15) >> 2) + 4 * (u_ >> 4) + (u_ & 3);
  const unsigned short* Vg = v + base + (size_t)rp * E + dcv;

  const int rx = (fr & 7) << 3;

  // prologue: K chunk 0 -> LDS (in flight), V chunk 0 -> regs (in flight)
  gll16(Kg, &Ksb[wave * 1024]);
  gll16(Kg + 8 * (size_t)E, &Ksb[wave * 1024 + 512]);
  u32x4 va = *(const u32x4*)(Vg);
  u32x4 vb = *(const u32x4*)(Vg + E);

  int cur = 0;
  for (int t = 0; t < 32; t++) {
    const int nxt = cur ^ 4096;

    __syncthreads();  // A: drains K[t] + va/vb — all issued a full phase ago

    // stage Vt from regs; overlaps with S^T below (different consumers)
#pragma unroll
    for (int w = 0; w < 4; w++) {
      uint32_t lo = __builtin_amdgcn_perm(vb[w], va[w], 0x05040100u);
      uint32_t hi = __builtin_amdgcn_perm(vb[w], va[w], 0x07060302u);
      int d = dcv + 2 * w;
      *(uint32_t*)&Vtb[d * 64 + (slot ^ ((2 * w) << 3))] = lo;
      *(uint32_t*)&Vtb[(d + 1) * 64 + (slot ^ ((2 * w + 1) << 3))] = hi;
    }

    // S^T: reads Ksb[cur] only (visible since barrier A)
    f32x4 st[2][4] = {};
    __builtin_amdgcn_s_setprio(1);
#pragma unroll
    for (int ks = 0; ks < 2; ks++) {
#pragma unroll
      for (int tt = 0; tt < 4; tt++) {
        bf16x8 ak = *(const bf16x8*)&Ksb[cur + (tt * 16 + fr) * 64 +
                                         ((ks * 32 + fq * 8) ^ rx)];
        st[0][tt] = __builtin_amdgcn_mfma_f32_16x16x32_bf16(ak, aq[0][ks], st[0][tt], 0, 0, 0);
        st[1][tt] = __builtin_amdgcn_mfma_f32_16x16x32_bf16(ak, aq[1][ks], st[1][tt], 0, 0, 0);
      }
    }
    __builtin_amdgcn_s_setprio(0);

    __syncthreads();  // B: Vt visible; no vmem outstanding -> free drain

    // prefetch chunk t+1: K -> LDS[nxt] (zero reg cost), V -> regs (8 VGPR,
    // live across exp2+PV; drained for free at next barrier A)
    if (t < 31) {
      const size_t poff = (size_t)(t + 1) * 64 * E;
      gll16(Kg + poff, &Ksb[nxt + wave * 1024]);
      gll16(Kg + poff + 8 * (size_t)E, &Ksb[nxt + wave * 1024 + 512]);
      va = *(const u32x4*)(Vg + poff);
      vb = *(const u32x4*)(Vg + poff + E);
    }

    // exp2 (scale pre-folded into q) + bf16 via scalar casts (HW cvt_pk)
    bf16x8 bp[2][2];  // [c][qg]
#pragma unroll
    for (int c = 0; c < 2; c++)
#pragma unroll
      for (int qg = 0; qg < 2; qg++) {
        bf16x8 vv;
#pragma unroll
        for (int j = 0; j < 8; j++)
          vv[j] = (__bf16)__builtin_amdgcn_exp2f(st[qg][2 * c + (j >> 2)][j & 3]);
        bp[c][qg] = vv;
      }

    // PV: reads Vtb (visible since barrier B)
    __builtin_amdgcn_s_setprio(1);
#pragma unroll
    for (int c = 0; c < 2; c++) {
#pragma unroll
      for (int dt = 0; dt < 4; dt++) {
        bf16x8 av = *(const bf16x8*)&Vtb[(dt * 16 + fr) * 64 +
                                         ((c * 32 + fq * 8) ^ rx)];
        ot[0][dt] = __builtin_amdgcn_mfma_f32_16x16x32_bf16(av, bp[c][0], ot[0][dt], 0, 0, 0);
        ot[1][dt] = __builtin_amdgcn_mfma_f32_16x16x32_bf16(av, bp[c][1], ot[1][dt], 0, 0, 0);
      }
      osum[0] = __builtin_amdgcn_mfma_f32_16x16x32_bf16(onesf, bp[c][0], osum[0], 0, 0, 0);
      osum[1] = __builtin_amdgcn_mfma_f32_16x16x32_bf16(onesf, bp[c][1], osum[1], 0, 0, 0);
    }
    __builtin_amdgcn_s_setprio(0);

    cur = nxt;
  }

#pragma unroll
  for (int qg = 0; qg < 2; qg++) {
    float inv = 1.0f / osum[qg][0];
    size_t rowbase = base + (size_t)(q0 + qg * 64 + wave * 16 + fr) * E;
#pragma unroll
    for (int dt = 0; dt < 4; dt++) {
      uint32_t w0 = rhu2(ot[qg][dt][0] * inv, ot[qg][dt][1] * inv);
      uint32_t w1 = rhu2(ot[qg][dt][2] * inv, ot[qg][dt][3] * inv);
      *(uint32_t*)&o[rowbase + dt * 16 + fq * 4] = w0;
      *(uint32_t*)&o[rowbase + dt * 16 + fq * 4 + 2] = w1;
    }
  }
}

// ---------------------------------------------------------------------------
// ws: 3 x 1M (weights) + 3 x 8M (q/k/v) shorts = 54 MB.
// hidden_states fp32 is now consumed directly by the QKV GEMM (AF32 staging)
// -> no cvt kernel, no hsb buffer. woT reuses wqT's slot (transposed only
// after the QKV GEMM has consumed wqT). Final GEMM writes fp32 to d_out.
// ---------------------------------------------------------------------------
extern "C" void kernel_launch(void* const* d_in, const int* in_sizes, int n_in,
                              void* d_out, int out_size, void* d_ws, size_t ws_size,
                              hipStream_t stream) {
  const float* hs = (const float*)d_in[0];
  const float* wq = (const float*)d_in[1];
  const float* wk = (const float*)d_in[2];
  const float* wv = (const float*)d_in[3];
  const float* wo = (const float*)d_in[4];
  unsigned short* ws = (unsigned short*)d_ws;

  unsigned short* wqT = ws;
  unsigned short* wkT = ws + 1048576;
  unsigned short* wvT = ws + 2097152;
  unsigned short* woT = wqT;
  unsigned short* qb  = ws + 3145728;
  unsigned short* kb  = qb + 8388608;
  unsigned short* vb  = kb + 8388608;
  unsigned short* ob  = qb;
  float* out = (float*)d_out;

  const int M = 8192, N = 1024, K = 1024;
  const float KSC = 0.125f * 1.44269504088896341f;  // head_scale * log2(e)

  dim3 tb(32, 8);
  transpose_w3<<<dim3(32, 32, 3), tb, 0, stream>>>(wq, wk, wv, wqT, wkT, wvT);

  gemm3<unsigned short, true><<<dim3(M / 128, N / 128, 3), 256, 0, stream>>>(
      nullptr, hs, wqT, wkT, wvT, qb, kb, vb, M, N, K, KSC);

  transpose_w<<<dim3(32, 32), tb, 0, stream>>>(wo, woT);

  attn_kernel<<<dim3(2048 / 128, 64), 256, 0, stream>>>(qb, kb, vb, ob);

  gemm3<float, false><<<dim3(M / 128, N / 128, 1), 256, 0, stream>>>(
      ob, nullptr, woT, woT, woT, out, out, out, M, N, K, 1.0f);
}

// Round 9
// 256.692 us; speedup vs baseline: 1.0857x; 1.0857x over previous
//
#include <hip/hip_runtime.h>
#include <stdint.h>

typedef __attribute__((ext_vector_type(8))) unsigned short ushort8;
typedef __attribute__((ext_vector_type(8))) __bf16 bf16x8;
typedef __attribute__((ext_vector_type(4))) float f32x4;
typedef __attribute__((ext_vector_type(4))) uint32_t u32x4;

__device__ __forceinline__ unsigned short f2bf(float f) {
  union { float f; uint32_t u; } x; x.f = f;
  uint32_t u = x.u;
  uint32_t r = (u + 0x7fffu + ((u >> 16) & 1u)) >> 16;
  return (unsigned short)r;
}

__device__ __forceinline__ uint32_t pack_bf2(float lo, float hi) {
  return (uint32_t)f2bf(lo) | ((uint32_t)f2bf(hi) << 16);
}

// round-half-up bf16 pair pack: 2 adds + 1 v_perm (≡ RNE for positive non-ties)
__device__ __forceinline__ uint32_t rhu2(float lo, float hi) {
  union { float f; uint32_t u; } a, b; a.f = lo; b.f = hi;
  return __builtin_amdgcn_perm(b.u + 0x8000u, a.u + 0x8000u, 0x07060302u);
}

__device__ __forceinline__ void store_c(unsigned short* p, float v) { *p = f2bf(v); }
__device__ __forceinline__ void store_c(float* p, float v) { *p = v; }

__device__ __forceinline__ void gll16(const unsigned short* g, unsigned short* l) {
  __builtin_amdgcn_global_load_lds((const __attribute__((address_space(1))) void*)g,
                                   (__attribute__((address_space(3))) void*)l,
                                   16, 0, 0);
}

// ---------------------------------------------------------------------------
// fp32 -> bf16 convert (RNE). One thread = 4 elements.
// ---------------------------------------------------------------------------
__global__ __launch_bounds__(256) void cvt_f32_bf16(
    const float* __restrict__ x, unsigned short* __restrict__ y, int n4) {
  int i = blockIdx.x * 256 + threadIdx.x;
  if (i >= n4) return;
  float4 v = *(const float4*)(x + (size_t)i * 4);
  uint2 p; p.x = pack_bf2(v.x, v.y); p.y = pack_bf2(v.z, v.w);
  *(uint2*)(y + (size_t)i * 4) = p;
}

// ---------------------------------------------------------------------------
// Weight transpose + convert: WT[n][k] = bf16(W[k][n]), 1024x1024 fp32 in.
// Batched x3 (wq/wk/wv) via blockIdx.z; single version kept for wo.
// ---------------------------------------------------------------------------
__device__ __forceinline__ void transpose_body(const float* W, unsigned short* WT) {
  __shared__ unsigned short tile[32][33];
  int c0 = blockIdx.x * 32, r0 = blockIdx.y * 32;
  int x = threadIdx.x, y = threadIdx.y;
#pragma unroll
  for (int i = 0; i < 32; i += 8)
    tile[y + i][x] = f2bf(W[(size_t)(r0 + y + i) * 1024 + c0 + x]);
  __syncthreads();
#pragma unroll
  for (int i = 0; i < 32; i += 8)
    WT[(size_t)(c0 + y + i) * 1024 + r0 + x] = tile[x][y + i];
}

__global__ void transpose_w(const float* __restrict__ W,
                            unsigned short* __restrict__ WT) {
  transpose_body(W, WT);
}

__global__ void transpose_w3(const float* W0, const float* W1, const float* W2,
                             unsigned short* T0, unsigned short* T1,
                             unsigned short* T2) {
  const float* W = (blockIdx.z == 0) ? W0 : (blockIdx.z == 1) ? W1 : W2;
  unsigned short* WT = (blockIdx.z == 0) ? T0 : (blockIdx.z == 1) ? T1 : T2;
  transpose_body(W, WT);
}

// ---------------------------------------------------------------------------
// GEMM (gemm3, R13/R16 verified-best — restored verbatim after R17's AF32
// fusion regressed it 85 -> 106 µs): C[M,N] = A[M,K]*B[K,N] given BT[N,K].
// 128x128 tile, BK=64, 256 thr (4 waves as 2m x 2n, each 64x64 out).
// Double-buffered LDS = 64 KB -> 2 blocks/CU (TLP beats pipeline depth:
// R12/R15 1-block/CU both regressed; R17 reg-staged A also regressed).
// ONE barrier per K-step; STAGE(t+1) after the barrier so never drained.
// Both-sides XOR swizzle: LDS chunk j of row r holds global chunk j^(r&7);
// gll16 dest linear, source pre-swizzled (lane-constant), reads XOR.
// sc0: epilogue scale when blockIdx.z == 0 (folds attn head_scale*log2e
// into the q projection; 1.0f elsewhere).
// ---------------------------------------------------------------------------
template <typename OutT>
__global__ __launch_bounds__(256, 2) void gemm3(
    const unsigned short* A,
    const unsigned short* BT0, const unsigned short* BT1, const unsigned short* BT2,
    OutT* C0, OutT* C1, OutT* C2,
    int M, int N, int K, float sc0) {
  const unsigned short* BT = (blockIdx.z == 0) ? BT0 : (blockIdx.z == 1) ? BT1 : BT2;
  OutT* C = (blockIdx.z == 0) ? C0 : (blockIdx.z == 1) ? C1 : C2;
  const float sc = (blockIdx.z == 0) ? sc0 : 1.0f;

  __shared__ __attribute__((aligned(16))) unsigned short As[2][128 * 64];
  __shared__ __attribute__((aligned(16))) unsigned short Bs[2][128 * 64];

  const int tid = threadIdx.x;
  const int wave = tid >> 6, lane = tid & 63;
  const int fr = lane & 15, fq = lane >> 4;
  const int wm = wave >> 1, wn = wave & 1;
  const int bm = blockIdx.x * 128, bn = blockIdx.y * 128;

  const int r8 = tid >> 3, c8 = tid & 7;
  const int s8 = c8 ^ (r8 & 7);
  const unsigned short* Ag = A + (size_t)(bm + r8) * K + s8 * 8;
  const unsigned short* Bg = BT + (size_t)(bn + r8) * K + s8 * 8;

  f32x4 acc[4][4] = {};
  const int rx = fr & 7;  // read-side swizzle (16B-chunk units)

  const int NT = K >> 6;

#pragma unroll
  for (int i = 0; i < 4; i++) {
    gll16(Ag + (size_t)(i * 32) * K, &As[0][(i * 32 + wave * 8) * 64]);
    gll16(Bg + (size_t)(i * 32) * K, &Bs[0][(i * 32 + wave * 8) * 64]);
  }

  int cur = 0;
  for (int t = 0; t < NT; ++t) {
    __syncthreads();  // drains STAGE(t) (in flight one full compute phase)

    if (t + 1 < NT) {
      const int b = cur ^ 1;
      const size_t k0 = (size_t)(t + 1) * 64;
#pragma unroll
      for (int i = 0; i < 4; i++) {
        gll16(Ag + k0 + (size_t)(i * 32) * K, &As[b][(i * 32 + wave * 8) * 64]);
        gll16(Bg + k0 + (size_t)(i * 32) * K, &Bs[b][(i * 32 + wave * 8) * 64]);
      }
    }

#pragma unroll
    for (int kh = 0; kh < 2; ++kh) {
      bf16x8 af[4], bfr[4];
#pragma unroll
      for (int mt = 0; mt < 4; mt++)
        af[mt] = *(const bf16x8*)&As[cur][(wm * 64 + mt * 16 + fr) * 64 +
                                          (((kh * 4 + fq) ^ rx) * 8)];
#pragma unroll
      for (int nt = 0; nt < 4; nt++)
        bfr[nt] = *(const bf16x8*)&Bs[cur][(wn * 64 + nt * 16 + fr) * 64 +
                                           (((kh * 4 + fq) ^ rx) * 8)];
#pragma unroll
      for (int mt = 0; mt < 4; mt++)
#pragma unroll
        for (int nt = 0; nt < 4; nt++)
          acc[mt][nt] = __builtin_amdgcn_mfma_f32_16x16x32_bf16(af[mt], bfr[nt], acc[mt][nt], 0, 0, 0);
    }
    cur ^= 1;
  }

#pragma unroll
  for (int mt = 0; mt < 4; mt++)
#pragma unroll
    for (int nt = 0; nt < 4; nt++)
#pragma unroll
      for (int r = 0; r < 4; r++) {
        int row = bm + wm * 64 + mt * 16 + fq * 4 + r;
        int col = bn + wn * 64 + nt * 16 + fr;
        store_c(&C[(size_t)row * N + col], acc[mt][nt][r] * sc);
      }
}

// ---------------------------------------------------------------------------
// Flash attention R17 (kept, now isolated for A/B vs R16's 81.4 µs):
// R16 structure (T14 async V, free-drain barriers) + softmax output via
// scalar float->bf16 casts (compiler emits v_cvt_pk_bf16_f32 per m240)
// instead of rhu2 bit-packing.
// ---------------------------------------------------------------------------
__global__ __launch_bounds__(256, 4) void attn_kernel(
    const unsigned short* q, const unsigned short* k,
    const unsigned short* v, unsigned short* o) {
  const int S = 2048, E = 1024;
  __shared__ __attribute__((aligned(16))) unsigned short Ksb[2 * 64 * 64];
  __shared__ __attribute__((aligned(16))) unsigned short Vtb[64 * 64];

  const int tid = threadIdx.x;
  const int wave = tid >> 6, lane = tid & 63;
  const int fr = lane & 15, fq = lane >> 4;
  const int q0 = blockIdx.x * 128;
  const int bh = blockIdx.y;
  const int b = bh >> 4, h = bh & 15;
  const size_t base = ((size_t)b * S) * E + (size_t)h * 64;

  bf16x8 aq[2][2];
#pragma unroll
  for (int qg = 0; qg < 2; qg++)
#pragma unroll
    for (int ks = 0; ks < 2; ks++)
      aq[qg][ks] = *(const bf16x8*)&q[base +
          (size_t)(q0 + qg * 64 + wave * 16 + fr) * E + ks * 32 + fq * 8];

  ushort8 ones_u;
#pragma unroll
  for (int j = 0; j < 8; j++) ones_u[j] = 0x3F80;  // bf16 1.0
  bf16x8 onesf = *(bf16x8*)&ones_u;

  f32x4 ot[2][4] = {};
  f32x4 osum[2] = {};

  const int srow = lane >> 3;
  const int scol = (((lane & 7) ^ srow) << 3);
  const unsigned short* Kg = k + base + (size_t)(wave * 16 + srow) * E + scol;

  const int rp = (tid & 31) * 2;
  const int dcv = (tid >> 5) * 8;
  const int u_ = rp & 31;
  const int slot = 32 * (rp >> 5) + 8 * ((u_ & 15) >> 2) + 4 * (u_ >> 4) + (u_ & 3);
  const unsigned short* Vg = v + base + (size_t)rp * E + dcv;

  const int rx = (fr & 7) << 3;

  // prologue: K chunk 0 -> LDS (in flight), V chunk 0 -> regs (in flight)
  gll16(Kg, &Ksb[wave * 1024]);
  gll16(Kg + 8 * (size_t)E, &Ksb[wave * 1024 + 512]);
  u32x4 va = *(const u32x4*)(Vg);
  u32x4 vb = *(const u32x4*)(Vg + E);

  int cur = 0;
  for (int t = 0; t < 32; t++) {
    const int nxt = cur ^ 4096;

    __syncthreads();  // A: drains K[t] + va/vb — all issued a full phase ago

    // stage Vt from regs; overlaps with S^T below (different consumers)
#pragma unroll
    for (int w = 0; w < 4; w++) {
      uint32_t lo = __builtin_amdgcn_perm(vb[w], va[w], 0x05040100u);
      uint32_t hi = __builtin_amdgcn_perm(vb[w], va[w], 0x07060302u);
      int d = dcv + 2 * w;
      *(uint32_t*)&Vtb[d * 64 + (slot ^ ((2 * w) << 3))] = lo;
      *(uint32_t*)&Vtb[(d + 1) * 64 + (slot ^ ((2 * w + 1) << 3))] = hi;
    }

    // S^T: reads Ksb[cur] only (visible since barrier A)
    f32x4 st[2][4] = {};
    __builtin_amdgcn_s_setprio(1);
#pragma unroll
    for (int ks = 0; ks < 2; ks++) {
#pragma unroll
      for (int tt = 0; tt < 4; tt++) {
        bf16x8 ak = *(const bf16x8*)&Ksb[cur + (tt * 16 + fr) * 64 +
                                         ((ks * 32 + fq * 8) ^ rx)];
        st[0][tt] = __builtin_amdgcn_mfma_f32_16x16x32_bf16(ak, aq[0][ks], st[0][tt], 0, 0, 0);
        st[1][tt] = __builtin_amdgcn_mfma_f32_16x16x32_bf16(ak, aq[1][ks], st[1][tt], 0, 0, 0);
      }
    }
    __builtin_amdgcn_s_setprio(0);

    __syncthreads();  // B: Vt visible; no vmem outstanding -> free drain

    // prefetch chunk t+1: K -> LDS[nxt] (zero reg cost), V -> regs (8 VGPR,
    // live across exp2+PV; drained for free at next barrier A)
    if (t < 31) {
      const size_t poff = (size_t)(t + 1) * 64 * E;
      gll16(Kg + poff, &Ksb[nxt + wave * 1024]);
      gll16(Kg + poff + 8 * (size_t)E, &Ksb[nxt + wave * 1024 + 512]);
      va = *(const u32x4*)(Vg + poff);
      vb = *(const u32x4*)(Vg + poff + E);
    }

    // exp2 (scale pre-folded into q) + bf16 via scalar casts (HW cvt_pk)
    bf16x8 bp[2][2];  // [c][qg]
#pragma unroll
    for (int c = 0; c < 2; c++)
#pragma unroll
      for (int qg = 0; qg < 2; qg++) {
        bf16x8 vv;
#pragma unroll
        for (int j = 0; j < 8; j++)
          vv[j] = (__bf16)__builtin_amdgcn_exp2f(st[qg][2 * c + (j >> 2)][j & 3]);
        bp[c][qg] = vv;
      }

    // PV: reads Vtb (visible since barrier B)
    __builtin_amdgcn_s_setprio(1);
#pragma unroll
    for (int c = 0; c < 2; c++) {
#pragma unroll
      for (int dt = 0; dt < 4; dt++) {
        bf16x8 av = *(const bf16x8*)&Vtb[(dt * 16 + fr) * 64 +
                                         ((c * 32 + fq * 8) ^ rx)];
        ot[0][dt] = __builtin_amdgcn_mfma_f32_16x16x32_bf16(av, bp[c][0], ot[0][dt], 0, 0, 0);
        ot[1][dt] = __builtin_amdgcn_mfma_f32_16x16x32_bf16(av, bp[c][1], ot[1][dt], 0, 0, 0);
      }
      osum[0] = __builtin_amdgcn_mfma_f32_16x16x32_bf16(onesf, bp[c][0], osum[0], 0, 0, 0);
      osum[1] = __builtin_amdgcn_mfma_f32_16x16x32_bf16(onesf, bp[c][1], osum[1], 0, 0, 0);
    }
    __builtin_amdgcn_s_setprio(0);

    cur = nxt;
  }

#pragma unroll
  for (int qg = 0; qg < 2; qg++) {
    float inv = 1.0f / osum[qg][0];
    size_t rowbase = base + (size_t)(q0 + qg * 64 + wave * 16 + fr) * E;
#pragma unroll
    for (int dt = 0; dt < 4; dt++) {
      uint32_t w0 = rhu2(ot[qg][dt][0] * inv, ot[qg][dt][1] * inv);
      uint32_t w1 = rhu2(ot[qg][dt][2] * inv, ot[qg][dt][3] * inv);
      *(uint32_t*)&o[rowbase + dt * 16 + fq * 4] = w0;
      *(uint32_t*)&o[rowbase + dt * 16 + fq * 4 + 2] = w1;
    }
  }
}

// ---------------------------------------------------------------------------
// ws: 3 x 1M (weights) + 3 x 8M (q/k/v) shorts = 54 MB.
// bf16 hidden_states lives in d_out's first 16 MB (dead before final GEMM).
// woT reuses wqT's slot (transposed only after the QKV GEMM has consumed
// wqT). Final GEMM writes fp32 to d_out.
// ---------------------------------------------------------------------------
extern "C" void kernel_launch(void* const* d_in, const int* in_sizes, int n_in,
                              void* d_out, int out_size, void* d_ws, size_t ws_size,
                              hipStream_t stream) {
  const float* hs = (const float*)d_in[0];
  const float* wq = (const float*)d_in[1];
  const float* wk = (const float*)d_in[2];
  const float* wv = (const float*)d_in[3];
  const float* wo = (const float*)d_in[4];
  unsigned short* ws = (unsigned short*)d_ws;

  unsigned short* wqT = ws;
  unsigned short* wkT = ws + 1048576;
  unsigned short* wvT = ws + 2097152;
  unsigned short* woT = wqT;
  unsigned short* qb  = ws + 3145728;
  unsigned short* kb  = qb + 8388608;
  unsigned short* vb  = kb + 8388608;
  unsigned short* ob  = qb;
  unsigned short* hsb = (unsigned short*)d_out;
  float* out = (float*)d_out;

  const int M = 8192, N = 1024, K = 1024;
  const float KSC = 0.125f * 1.44269504088896341f;  // head_scale * log2(e)

  cvt_f32_bf16<<<dim3(M * K / 4 / 256), 256, 0, stream>>>(hs, hsb, M * K / 4);

  dim3 tb(32, 8);
  transpose_w3<<<dim3(32, 32, 3), tb, 0, stream>>>(wq, wk, wv, wqT, wkT, wvT);

  gemm3<unsigned short><<<dim3(M / 128, N / 128, 3), 256, 0, stream>>>(
      hsb, wqT, wkT, wvT, qb, kb, vb, M, N, K, KSC);

  transpose_w<<<dim3(32, 32), tb, 0, stream>>>(wo, woT);

  attn_kernel<<<dim3(2048 / 128, 64), 256, 0, stream>>>(qb, kb, vb, ob);

  gemm3<float><<<dim3(M / 128, N / 128, 1), 256, 0, stream>>>(
      ob, woT, woT, woT, out, out, out, M, N, K, 1.0f);
}